// Round 3
// baseline (33615.308 us; speedup 1.0000x reference)
//
#include <hip/hip_runtime.h>

typedef unsigned short u16;
typedef unsigned int u32;

typedef __attribute__((ext_vector_type(8))) short bhalf8;
typedef __attribute__((ext_vector_type(4))) float floatx4;

#define NB 32
#define TE 512
#define LD 128
#define H1 1024
#define KD 128
#define XW 1408                 // [x(256)|ctx(128)|h1(1024)]
#define XELT 45056              // 32*1408

__device__ __forceinline__ float bfl(u32 u){ return __uint_as_float(u << 16); }
__device__ __forceinline__ float bfh(u32 u){ return __uint_as_float(u & 0xffff0000u); }
__device__ __forceinline__ float bf1(u16 v){ return __uint_as_float(((u32)v) << 16); }
__device__ __forceinline__ u16 f2bf(float f){
  u32 x = __float_as_uint(f);
  return (u16)((x + 0x7fffu + ((x >> 16) & 1u)) >> 16);
}
__device__ __forceinline__ float sigf(float x){ return 1.0f / (1.0f + __expf(-x)); }

// grid barrier: monotone counter, agent-scope atomics, L1-invalidating fences
__device__ __forceinline__ void gbar(unsigned* cnt, unsigned target){
  __syncthreads();
  if (threadIdx.x == 0){
    __threadfence();   // release: drain my block's global writes
    __hip_atomic_fetch_add(cnt, 1u, __ATOMIC_RELAXED, __HIP_MEMORY_SCOPE_AGENT);
    while (__hip_atomic_load(cnt, __ATOMIC_RELAXED, __HIP_MEMORY_SCOPE_AGENT) < target)
      __builtin_amdgcn_s_sleep(2);
  }
  __syncthreads();
  __threadfence();     // acquire: invalidate L1 so we see other blocks' writes
}

__global__ void k_init0(u16* __restrict__ Xbuf, u16* __restrict__ h2buf,
                        unsigned* __restrict__ barcnt){
  int idx = blockIdx.x * 256 + threadIdx.x;
  if (idx == 0) *barcnt = 0u;
  // zero X double buffer (2*45056) then h2 double buffer (2*4096)
  if (idx < 2 * XELT) Xbuf[idx] = 0;
  int j = idx - 2 * XELT;
  if (j >= 0 && j < 2 * 4096) h2buf[j] = 0;
}

__global__ __launch_bounds__(256, 2) void k_persist(
    const float* __restrict__ key, const float* __restrict__ values,
    const int* __restrict__ elen, const int* __restrict__ text,
    const float* __restrict__ emb,
    const float* __restrict__ Wih1, const float* __restrict__ Whh1,
    const float* __restrict__ bih1, const float* __restrict__ bhh1,
    const float* __restrict__ Wih2, const float* __restrict__ Whh2,
    const float* __restrict__ bih2, const float* __restrict__ bhh2,
    u16* W1cat, u16* Xbuf, u16* h2buf, float* pc, u16* aall, unsigned* barcnt)
{
  __shared__ u16 s_w2[4 * 1152];       // gates2 weight slice (unit u2, 4 gates), persistent
  __shared__ u16 s_key[32 * 128];      // key chunk [T][d] bf16 pairs, persistent
  __shared__ u16 s_val[128 * 32];      // values chunk transposed [d][T], persistent
  __shared__ float s_red[2048];        // phase A partials / phase C scratch
  __shared__ float s_c1[128];          // c1[us*32+n], persistent (A-blocks)
  __shared__ float s_c2[8];            // c2[nl], persistent (B role)
  __shared__ float s_b1[16];
  __shared__ float s_b2[4];
  __shared__ float s_en[32];
  __shared__ float s_p[32];
  __shared__ float s_misc[4];

  const int tid = threadIdx.x;
  const int bid = blockIdx.x;

  // ---------------- init phase ----------------
  {
    // W1cat bf16: rows bid*8..+7 ; [0:384)=Wih1 row, [384:1408)=Whh1 row
    for (int rr = 0; rr < 8; rr++){
      int row = bid * 8 + rr;
      const float* s1 = Wih1 + (size_t)row * 384;
      const float* s2 = Whh1 + (size_t)row * 1024;
      u16* dst = W1cat + (size_t)row * XW;
      for (int c = tid; c < XW; c += 256)
        dst[c] = f2bf(c < 384 ? s1[c] : s2[c - 384]);
    }
    // W2 slice -> LDS (unit u2, rows {u2,128+u2,256+u2,384+u2}, K=[h1|h2])
    int u2 = bid >> 2;
    for (int i = tid; i < 4608; i += 256){
      int r = i / 1152, k = i - r * 1152;
      int row = r * 128 + u2;
      float v = (k < 1024) ? Wih2[(size_t)row * 1024 + k]
                           : Whh2[(size_t)row * 128 + (k - 1024)];
      s_w2[i] = f2bf(v);
    }
    if (tid < 4){
      int row = tid * 128 + u2;
      s_b2[tid] = bih2[row] + bhh2[row];
    }
    if (tid < 8) s_c2[tid] = 0.0f;
    // key/values chunk -> LDS
    int cn = bid & 31, tc = bid >> 5;
    for (int i = tid; i < 4096; i += 256){
      int tl = i >> 7, dd = i & 127;
      size_t g = ((size_t)cn * TE + tc * 32 + tl) * KD + dd;
      s_key[tl * 128 + dd] = f2bf(key[g]);
      s_val[dd * 32 + tl]  = f2bf(values[g]);
    }
    if (bid < 256){
      int u0 = bid * 4;
      if (tid < 16){
        int row = (tid >> 2) * 1024 + u0 + (tid & 3);
        s_b1[tid] = bih1[row] + bhh1[row];
      }
      if (tid < 128) s_c1[tid] = 0.0f;
    }
    if (bid < 32){
      int n = bid;
      u16* X0 = Xbuf + (size_t)n * XW;
      for (int c = tid; c < 384; c += 256){
        float v = (c < 256) ? emb[256 + c] : values[(size_t)n * TE * KD + (c - 256)];
        X0[c] = f2bf(v);
      }
    }
  }
  unsigned barno = 1;
  gbar(barcnt, barno * 512u);

  // ---------------- step loop ----------------
  for (int t = 0; t < 128; t++){
    // ===== Phase A: gates1 MFMA + cell1 (blocks 0..255) =====
    if (bid < 256){
      int u0 = bid * 4;
      int lane = tid & 63, wv = tid >> 6;
      int c = lane & 15, quad = lane >> 4;
      int rowm = (c >> 2) * 1024 + u0 + (c & 3);
      const u16* Xc = Xbuf + (size_t)(t & 1) * XELT;
      int kb = wv * 352 + quad * 8;
      const u16* a0p = Xc + (size_t)c * XW + kb;
      const u16* a1p = Xc + (size_t)(16 + c) * XW + kb;
      const u16* bp  = W1cat + (size_t)rowm * XW + kb;
      floatx4 acc0 = {0.f,0.f,0.f,0.f}, acc1 = {0.f,0.f,0.f,0.f};
      #pragma unroll
      for (int kk = 0; kk < 11; kk++){
        bhalf8 a0 = *(const bhalf8*)(a0p + kk * 32);
        bhalf8 a1 = *(const bhalf8*)(a1p + kk * 32);
        bhalf8 bb = *(const bhalf8*)(bp  + kk * 32);
        acc0 = __builtin_amdgcn_mfma_f32_16x16x32_bf16(a0, bb, acc0, 0, 0, 0);
        acc1 = __builtin_amdgcn_mfma_f32_16x16x32_bf16(a1, bb, acc1, 0, 0, 0);
      }
      #pragma unroll
      for (int r = 0; r < 4; r++){
        s_red[((wv * 2 + 0) * 4 + r) * 64 + lane] = acc0[r];
        s_red[((wv * 2 + 1) * 4 + r) * 64 + lane] = acc1[r];
      }
      __syncthreads();
      if (tid < 128){
        int n = tid & 31, us = tid >> 5;
        int tau = n >> 4, q = (n & 15) >> 2, r = n & 3;
        float gv[4];
        #pragma unroll
        for (int g = 0; g < 4; g++){
          int cc = g * 4 + us;
          float s = s_b1[cc];
          #pragma unroll
          for (int w = 0; w < 4; w++)
            s += s_red[((w * 2 + tau) * 4 + r) * 64 + q * 16 + cc];
          gv[g] = s;
        }
        float gi = sigf(gv[0]), gf = sigf(gv[1]), gg = tanhf(gv[2]), go = sigf(gv[3]);
        float cn = gf * s_c1[tid] + gi * gg;
        s_c1[tid] = cn;
        float hn = go * tanhf(cn);
        u16* Xn = Xbuf + (size_t)((t + 1) & 1) * XELT;
        Xn[(size_t)n * XW + 384 + u0 + us] = f2bf(hn);
      }
    }
    barno++; gbar(barcnt, barno * 512u);

    // ===== Phase B: gates2 + cell2 (all blocks; unit u2, 8 batches) =====
    {
      int u2 = bid >> 2, ngrp = bid & 3;
      int nl = tid >> 5, l = tid & 31;
      int n = ngrp * 8 + nl;
      const u16* Xh1 = Xbuf + (size_t)((t + 1) & 1) * XELT + (size_t)n * XW + 384;
      const u16* h2p = h2buf + (size_t)((t & 1) ^ 1) * 4096 + n * 128;
      float a0 = 0.f, a1 = 0.f, a2 = 0.f, a3 = 0.f;
      int kb = l * 36;
      #pragma unroll 4
      for (int j = 0; j < 36; j++){
        int k = kb + j;
        float xv = (k < 1024) ? bf1(Xh1[k]) : bf1(h2p[k - 1024]);
        a0 += xv * bf1(s_w2[k]);
        a1 += xv * bf1(s_w2[1152 + k]);
        a2 += xv * bf1(s_w2[2304 + k]);
        a3 += xv * bf1(s_w2[3456 + k]);
      }
      #pragma unroll
      for (int off = 16; off > 0; off >>= 1){
        a0 += __shfl_xor(a0, off);
        a1 += __shfl_xor(a1, off);
        a2 += __shfl_xor(a2, off);
        a3 += __shfl_xor(a3, off);
      }
      if (l == 0){
        float gi = sigf(a0 + s_b2[0]);
        float gf = sigf(a1 + s_b2[1]);
        float gg = tanhf(a2 + s_b2[2]);
        float go = sigf(a3 + s_b2[3]);
        float cn = gf * s_c2[nl] + gi * gg;
        s_c2[nl] = cn;
        float hn = go * tanhf(cn);
        h2buf[(size_t)(t & 1) * 4096 + n * 128 + u2] = f2bf(hn);
      }
    }
    barno++; gbar(barcnt, barno * 512u);

    // ===== Phase C: attention partials (all blocks; n, T-chunk) =====
    {
      int cn = bid & 31, tc = bid >> 5;
      int wv = tid >> 6, lane = tid & 63;
      const u32* h2c = (const u32*)(h2buf + (size_t)(t & 1) * 4096 + cn * 128);
      u32 hp = h2c[lane];
      float h0 = bfl(hp), h1v = bfh(hp);
      int el = elen[cn];
      #pragma unroll
      for (int i = 0; i < 8; i++){
        int tl = wv * 8 + i;
        u32 kp = ((const u32*)s_key)[tl * 64 + lane];
        float e = bfl(kp) * h0 + bfh(kp) * h1v;
        #pragma unroll
        for (int off = 32; off > 0; off >>= 1) e += __shfl_xor(e, off);
        if (lane == 0)
          s_en[tl] = (tc * 32 + tl >= el) ? -1e9f : e;
      }
      __syncthreads();
      if (tid < 32){
        float m = -1e30f;
        #pragma unroll 8
        for (int j = 0; j < 32; j++) m = fmaxf(m, s_en[j]);
        s_p[tid] = __expf(s_en[tid] - m);
        if (tid == 0) s_misc[0] = m;
      }
      __syncthreads();
      int d = tid & 127, hh = tid >> 7;
      float acc = 0.f;
      #pragma unroll
      for (int j = 0; j < 16; j++){
        int tl = hh * 16 + j;
        acc += s_p[tl] * bf1(s_val[d * 32 + tl]);
      }
      s_red[hh * 128 + d] = acc;
      __syncthreads();
      float* rec = pc + ((size_t)cn * 16 + tc) * 132;
      if (tid < 128) rec[2 + tid] = s_red[tid] + s_red[128 + tid];
      else if (tid == 128){
        float ss = 0.f;
        #pragma unroll 8
        for (int j = 0; j < 32; j++) ss += s_p[j];
        rec[0] = s_misc[0];
        rec[1] = ss;
      }
    }
    barno++; gbar(barcnt, barno * 512u);

    // ===== Phase D: softmax combine -> ctx, aall row, next-step X prep (blocks 0..31) =====
    if (bid < 32){
      int n = bid;
      const float* rec = pc + (size_t)n * 16 * 132;
      float M = -1e30f;
      #pragma unroll
      for (int b = 0; b < 16; b++) M = fmaxf(M, rec[b * 132]);
      float S = 0.f;
      #pragma unroll
      for (int b = 0; b < 16; b++) S += __expf(rec[b * 132] - M) * rec[b * 132 + 1];
      float inv = 1.0f / S;
      u16* Xn = Xbuf + (size_t)((t + 1) & 1) * XELT + (size_t)n * XW;
      u16* arow = aall + ((size_t)t * NB + n) * 256;
      if (tid < 128){
        float acc = 0.f;
        #pragma unroll
        for (int b = 0; b < 16; b++)
          acc += __expf(rec[b * 132] - M) * rec[b * 132 + 2 + tid];
        u16 cb = f2bf(acc * inv);
        Xn[256 + tid] = cb;
        arow[128 + tid] = cb;
        arow[tid] = h2buf[(size_t)(t & 1) * 4096 + n * 128 + tid];
      }
      int tok = text[n * LD + t];
      Xn[tid] = f2bf(emb[(size_t)tok * 256 + tid]);
    }
    barno++; gbar(barcnt, barno * 512u);
  }
}

// ---- output GEMM: out[n][t][v] = aall[t*32+n][:256] . W_out[v][:256] + b_out[v]
__global__ __launch_bounds__(256) void k_out(
    const u16* __restrict__ aall, const float* __restrict__ wout,
    const float* __restrict__ bout, float* __restrict__ out)
{
  __shared__ __align__(16) u16 sA[128 * 136];
  __shared__ __align__(16) u16 sW[80 * 136];
  int tid = threadIdx.x;
  int vt = blockIdx.x, rt = blockIdx.y;
  int v0 = vt * 80, r0 = rt * 128;
  int rg = tid >> 4, vg = tid & 15;
  float acc[8][5];
  #pragma unroll
  for (int i = 0; i < 8; i++)
    #pragma unroll
    for (int j = 0; j < 5; j++) acc[i][j] = 0.0f;
  for (int kc = 0; kc < 2; kc++){
    int k0 = kc * 128;
    __syncthreads();
    for (int i = tid; i < 128 * 128; i += 256){
      int r = i >> 7, c = i & 127;
      sA[r * 136 + c] = aall[((size_t)(r0 + r)) * 256 + k0 + c];
    }
    for (int i = tid; i < 80 * 128; i += 256){
      int r = i >> 7, c = i & 127;
      sW[r * 136 + c] = f2bf(wout[((size_t)(v0 + r)) * 256 + k0 + c]);
    }
    __syncthreads();
    const u16* ap = sA + (rg * 8) * 136;
    const u16* wp = sW + (vg * 5) * 136;
    for (int kp = 0; kp < 64; kp++){
      u32 av[8], wv[5];
      #pragma unroll
      for (int i = 0; i < 8; i++) av[i] = *(const u32*)(ap + i * 136 + 2 * kp);
      #pragma unroll
      for (int j = 0; j < 5; j++) wv[j] = *(const u32*)(wp + j * 136 + 2 * kp);
      float wlo[5], whi[5];
      #pragma unroll
      for (int j = 0; j < 5; j++){ wlo[j] = bfl(wv[j]); whi[j] = bfh(wv[j]); }
      #pragma unroll
      for (int i = 0; i < 8; i++){
        float a0 = bfl(av[i]), a1 = bfh(av[i]);
        #pragma unroll
        for (int j = 0; j < 5; j++) acc[i][j] += a0 * wlo[j] + a1 * whi[j];
      }
    }
  }
  #pragma unroll
  for (int i = 0; i < 8; i++){
    int r = r0 + rg * 8 + i;
    int tt = r >> 5, nn = r & 31;
    size_t ob = ((size_t)nn * LD + tt) * 8000 + v0 + vg * 5;
    #pragma unroll
    for (int j = 0; j < 5; j++)
      out[ob + j] = acc[i][j] + bout[v0 + vg * 5 + j];
  }
}

extern "C" void kernel_launch(void* const* d_in, const int* in_sizes, int n_in,
                              void* d_out, int out_size, void* d_ws, size_t ws_size,
                              hipStream_t stream)
{
  const float* key    = (const float*)d_in[0];
  const float* values = (const float*)d_in[1];
  const int*   elen   = (const int*)d_in[2];
  const int*   text   = (const int*)d_in[3];
  const float* emb    = (const float*)d_in[4];
  const float* Wih1   = (const float*)d_in[5];
  const float* Whh1   = (const float*)d_in[6];
  const float* bih1   = (const float*)d_in[7];
  const float* bhh1   = (const float*)d_in[8];
  const float* Wih2   = (const float*)d_in[9];
  const float* Whh2   = (const float*)d_in[10];
  const float* bih2   = (const float*)d_in[11];
  const float* bhh2   = (const float*)d_in[12];
  const float* Wout   = (const float*)d_in[13];
  const float* bout   = (const float*)d_in[14];
  float* out = (float*)d_out;
  char* wsb = (char*)d_ws;

  unsigned* barcnt = (unsigned*)wsb;                          // 64 B
  u16* W1cat = (u16*)(wsb + 64);                              // 4096*1408*2 = 11534336
  u16* Xbuf  = (u16*)(wsb + 64 + 11534336);                   // 2*45056*2 = 180224
  u16* h2buf = (u16*)(wsb + 64 + 11534336 + 180224);          // 2*4096*2 = 16384
  float* pc  = (float*)(wsb + 64 + 11534336 + 180224 + 16384);// 32*16*132*4 = 270336
  u16* aall  = (u16*)(wsb + 64 + 11534336 + 180224 + 16384 + 270336); // 4096*256*2

  k_init0<<<384, 256, 0, stream>>>(Xbuf, h2buf, barcnt);
  k_persist<<<512, 256, 0, stream>>>(key, values, elen, text, emb,
                                     Wih1, Whh1, bih1, bhh1,
                                     Wih2, Whh2, bih2, bhh2,
                                     W1cat, Xbuf, h2buf, pc, aall, barcnt);
  k_out<<<dim3(100, 32), 256, 0, stream>>>(aall, Wout, bout, out);
}